// Round 1
// 163.149 us; speedup vs baseline: 1.0606x; 1.0606x over previous
//
#include <hip/hip_runtime.h>
#include <hip/hip_bf16.h>

#define BB 8
#define NN 2048
#define VV 256
#define HH 1024
#define CHK 64
#define RPC 32
constexpr float EPS = 1e-5f;

typedef __attribute__((ext_vector_type(4))) float floatx4;
typedef __attribute__((ext_vector_type(8))) short short8;

__device__ __forceinline__ void load_lds16(const void* g, void* l) {
    __builtin_amdgcn_global_load_lds((const __attribute__((address_space(1))) void*)g,
                                     (__attribute__((address_space(3))) void*)l, 16, 0, 0);
}
__device__ __forceinline__ float bf16s_to_f(short s) {
    unsigned u = ((unsigned)(unsigned short)s) << 16;
    return __builtin_bit_cast(float, u);
}

// ---------------------------------------------------------------------------
// K1: per-batch LayerNorms of row 0 (attn + mlp), sum0[b]=attn_row0 . qk_dir,
//     and v_bos = wo_w @ wv_bos  (block 8)
// ---------------------------------------------------------------------------
__global__ void prep_kernel(const float* __restrict__ h,
                            const float* __restrict__ g_attn, const float* __restrict__ b_attn,
                            const float* __restrict__ g_mlp,  const float* __restrict__ b_mlp,
                            const float* __restrict__ qk_dir,
                            const float* __restrict__ wo_w,  const float* __restrict__ wv_bos,
                            float* __restrict__ attn_row0, float* __restrict__ mlp_row0,
                            float* __restrict__ v_bos, float* __restrict__ sum0)
{
    int t = threadIdx.x;
    __shared__ float red[VV];
    if (blockIdx.x < BB) {
        int b = blockIdx.x;
        float x = h[(size_t)b * NN * VV + t];
        red[t] = x; __syncthreads();
        for (int s = 128; s > 0; s >>= 1) { if (t < s) red[t] += red[t + s]; __syncthreads(); }
        float m = red[0] * (1.0f / VV); __syncthreads();
        float xc = x - m;
        red[t] = xc * xc; __syncthreads();
        for (int s = 128; s > 0; s >>= 1) { if (t < s) red[t] += red[t + s]; __syncthreads(); }
        float var = red[0] * (1.0f / VV); __syncthreads();
        float inv = 1.0f / sqrtf(var + EPS);
        float an = xc * inv * g_attn[t] + b_attn[t];
        float mn = xc * inv * g_mlp[t] + b_mlp[t];
        attn_row0[b * VV + t] = an;
        mlp_row0[b * VV + t]  = mn;
        red[t] = an * qk_dir[t]; __syncthreads();
        for (int s = 128; s > 0; s >>= 1) { if (t < s) red[t] += red[t + s]; __syncthreads(); }
        if (t == 0) sum0[b] = red[0];
    } else {
        const float4* wp = reinterpret_cast<const float4*>(wo_w + (size_t)t * VV);
        const float4* vp = reinterpret_cast<const float4*>(wv_bos);
        float acc = 0.f;
        for (int j = 0; j < VV / 4; ++j) {
            float4 a = wp[j], b = vp[j];
            acc += a.x * b.x + a.y * b.y + a.z * b.z + a.w * b.w;
        }
        v_bos[t] = acc;
    }
}

// ---------------------------------------------------------------------------
// K2: fused pass over h: bf16 convert (BOS row swap), packed softmax weights
//     {W0, WP-WZ, WZ, 0}, scan chunk partials, AND weight bf16 conversion
//     (exactly 1 float4 per thread: 512 blocks x 256 thr = 131072 = 2*H*V/4).
// ---------------------------------------------------------------------------
__global__ __launch_bounds__(256) void scan_qkw_cvt_kernel(
    const float* __restrict__ h, const float* __restrict__ mlp_row0,
    const float* __restrict__ wv,
    const float* __restrict__ qk_bos, const float* __restrict__ qk_prev,
    const float* __restrict__ sum0,
    short* __restrict__ Xb,
    float* __restrict__ wpack,
    float* __restrict__ chunkSum,
    const float* __restrict__ w1, const float* __restrict__ w2,
    short* __restrict__ w1b, short* __restrict__ w2b)
{
    __shared__ float lds[4][VV];
    int wave = threadIdx.x >> 6, lane = threadIdx.x & 63;
    int b = blockIdx.x / CHK, c = blockIdx.x % CHK;
    int r0 = c * RPC + wave * 8;
    float4 wv4 = reinterpret_cast<const float4*>(wv)[lane];
    float4 qb4 = reinterpret_cast<const float4*>(qk_bos)[lane];
    float4 qp4 = reinterpret_cast<const float4*>(qk_prev)[lane];
    float s0b = sum0[b];
    float4 vsum = {0.f, 0.f, 0.f, 0.f};
#pragma unroll
    for (int rr = 0; rr < 8; ++rr) {
        int r = r0 + rr;
        size_t base = ((size_t)b * NN + r) * VV;
        float4 x = *reinterpret_cast<const float4*>(h + base + lane * 4);
        float4 xs = x;
        if (r == 0) xs = *reinterpret_cast<const float4*>(mlp_row0 + b * VV + lane * 4);
        __hip_bfloat16 c0 = __float2bfloat16(xs.x), c1 = __float2bfloat16(xs.y),
                       c2 = __float2bfloat16(xs.z), c3 = __float2bfloat16(xs.w);
        short4 pk;
        pk.x = *reinterpret_cast<short*>(&c0);
        pk.y = *reinterpret_cast<short*>(&c1);
        pk.z = *reinterpret_cast<short*>(&c2);
        pk.w = *reinterpret_cast<short*>(&c3);
        *reinterpret_cast<short4*>(Xb + base + lane * 4) = pk;
        if (r != 0) {
            vsum.x += bf16s_to_f(pk.x) * wv4.x; vsum.y += bf16s_to_f(pk.y) * wv4.y;
            vsum.z += bf16s_to_f(pk.z) * wv4.z; vsum.w += bf16s_to_f(pk.w) * wv4.w;
        }
        float s1 = x.x * qb4.x + x.y * qb4.y + x.z * qb4.z + x.w * qb4.w;
        float s2 = x.x * qp4.x + x.y * qp4.y + x.z * qp4.z + x.w * qp4.w;
        for (int off = 32; off > 0; off >>= 1) {
            s1 += __shfl_down(s1, off);
            s2 += __shfl_down(s2, off);
        }
        if (lane == 0) {
            int gid = b * NN + r;
            float W0, WP, WZ;
            if (r == 0) { W0 = 1.f; WP = 0.f; WZ = 0.f; }
            else if (r == 1) {
                float a = s1 * s0b + s2;
                float m = fmaxf(a, 0.f);
                float ea = expf(a - m), ez = expf(-m);
                float Z = ea + ez;
                W0 = ea / Z; WZ = ez / Z; WP = WZ;
            } else {
                float a = s1 * s0b;
                float m = fmaxf(fmaxf(a, s2), 0.f);
                float ea = expf(a - m), ed = expf(s2 - m), ez = expf(-m);
                float Z = ea + ed + (float)(r - 1) * ez;
                W0 = ea / Z; WP = ed / Z; WZ = ez / Z;
            }
            float4 wp4 = {W0, WP - WZ, WZ, 0.f};
            *reinterpret_cast<float4*>(wpack + (size_t)gid * 4) = wp4;
        }
    }
    reinterpret_cast<float4*>(lds[wave])[lane] = vsum;

    // fused weight conversion tail (independent of LDS contents above)
    {
        int gi = blockIdx.x * 256 + threadIdx.x;   // float4 index, exact cover
        size_t off = (size_t)gi * 4;
        const float* src; short* dst;
        if (off < (size_t)HH * VV) { src = w1 + off; dst = w1b + off; }
        else                       { src = w2 + (off - (size_t)HH * VV); dst = w2b + (off - (size_t)HH * VV); }
        float4 x = *reinterpret_cast<const float4*>(src);
        __hip_bfloat16 c0 = __float2bfloat16(x.x), c1 = __float2bfloat16(x.y),
                       c2 = __float2bfloat16(x.z), c3 = __float2bfloat16(x.w);
        short4 pk;
        pk.x = *reinterpret_cast<short*>(&c0);
        pk.y = *reinterpret_cast<short*>(&c1);
        pk.z = *reinterpret_cast<short*>(&c2);
        pk.w = *reinterpret_cast<short*>(&c3);
        *reinterpret_cast<short4*>(dst) = pk;
    }

    __syncthreads();
    int v = threadIdx.x;
    chunkSum[((size_t)b * CHK + c) * VV + v] = lds[0][v] + lds[1][v] + lds[2][v] + lds[3][v];
}

// K3: exclusive scan of chunk partials
__global__ void chunkscan_kernel(float* __restrict__ chunkSum)
{
    int b = blockIdx.x, v = threadIdx.x;
    float vals[CHK];
#pragma unroll
    for (int c = 0; c < CHK; ++c) vals[c] = chunkSum[(b * CHK + c) * VV + v];
    float run = 0.f;
#pragma unroll
    for (int c = 0; c < CHK; ++c) { float t = vals[c]; vals[c] = run; run += t; }
#pragma unroll
    for (int c = 0; c < CHK; ++c) chunkSum[(b * CHK + c) * VV + v] = vals[c];
}

// ---------------------------------------------------------------------------
// K4: fused MLP + attention emit.
//   Core GEMM loop identical to the verified mlp_fused3 (double-buffered DMA
//   staging, XOR seg-swizzle, GEMM1 32x16 / GEMM2 32x64 wave tiles).
//   Epilogue: oacc -> LDS (stride 260 floats: q-group aliasing is 2-way=free),
//   then 512 threads run the serial attention scan (1 v-column x 1 chunk
//   each; block's 64 rows = exactly 2 chunks) and write out = attn + mlp
//   in a single coalesced store. Kills attn_kernel + out read-modify-write.
// ---------------------------------------------------------------------------
__global__ __launch_bounds__(512) void mlp_fused4(const short* __restrict__ Xb,
                                                  const short* __restrict__ w1b,
                                                  const short* __restrict__ w2b,
                                                  const float* __restrict__ wv,
                                                  const float* __restrict__ v_bos,
                                                  const float* __restrict__ wpack,
                                                  const float* __restrict__ chunkSum,
                                                  float* __restrict__ out)
{
    __shared__ __align__(16) char smem[136 * 1024];
    short (*sW1)[64 * 256] = reinterpret_cast<short(*)[64 * 256]>(smem);           // 2 x 32 KB
    short (*sW2)[256 * 64] = reinterpret_cast<short(*)[256 * 64]>(smem + 65536);   // 2 x 32 KB
    short* sY = reinterpret_cast<short*>(smem + 131072);                            // 8 KB

    int wave = threadIdx.x >> 6, lane = threadIdx.x & 63;
    int wm = wave >> 2, wn = wave & 3;
    int ra = lane & 15, q = lane >> 4;
    int m0 = blockIdx.x * 64;

    // X fragments: rows of this wave's wm-half, full K=256
    short8 xf[8][2];
#pragma unroll
    for (int ks = 0; ks < 8; ++ks)
#pragma unroll
        for (int i = 0; i < 2; ++i)
            xf[ks][i] = *reinterpret_cast<const short8*>(
                Xb + (size_t)(m0 + wm * 32 + i * 16 + ra) * VV + ks * 32 + q * 8);

    floatx4 oacc[2][4];
#pragma unroll
    for (int i = 0; i < 2; ++i)
#pragma unroll
        for (int j = 0; j < 4; ++j) oacc[i][j] = floatx4{0.f, 0.f, 0.f, 0.f};

    auto stage = [&](int hc, int buf) {
#pragma unroll
        for (int it = 0; it < 4; ++it) {
            int g = wave * 4 + it;
            int n = g * 2 + (lane >> 5);
            int slot = lane & 31;
            load_lds16(w1b + (size_t)(hc * 64 + n) * VV + (slot ^ (n & 7)) * 8,
                       &sW1[buf][g * 512]);
        }
#pragma unroll
        for (int it = 0; it < 4; ++it) {
            int g = wave * 4 + it;
            int v = g * 8 + (lane >> 3);
            int slot = lane & 7;
            load_lds16(w2b + (size_t)v * HH + hc * 64 + (slot ^ (v & 7)) * 8,
                       &sW2[buf][g * 512]);
        }
    };

    stage(0, 0);
    for (int hc = 0; hc < 16; ++hc) {
        int p = hc & 1;
        __syncthreads();                 // buf[p] staged+visible; sY consumed
        if (hc < 15) stage(hc + 1, p ^ 1);

        // ---- GEMM1: Y[wm*32..+32][wn*16..+16] = X @ w1c^T ----
        floatx4 yacc[2];
        yacc[0] = floatx4{0.f, 0.f, 0.f, 0.f};
        yacc[1] = floatx4{0.f, 0.f, 0.f, 0.f};
        int nb = wn * 16 + ra;
#pragma unroll
        for (int ks = 0; ks < 8; ++ks) {
            short8 bfr = *reinterpret_cast<const short8*>(
                &sW1[p][nb * 256 + (((ks * 4 + q) ^ (ra & 7)) * 8)]);
#pragma unroll
            for (int i = 0; i < 2; ++i)
                yacc[i] = __builtin_amdgcn_mfma_f32_16x16x32_bf16(xf[ks][i], bfr, yacc[i], 0, 0, 0);
        }
        // relu -> bf16 -> sY (swizzled)
#pragma unroll
        for (int i = 0; i < 2; ++i)
#pragma unroll
            for (int reg = 0; reg < 4; ++reg) {
                int m = wm * 32 + i * 16 + q * 4 + reg;
                int ke = wn * 16 + ra;
                __hip_bfloat16 hb = __float2bfloat16(fmaxf(yacc[i][reg], 0.f));
                sY[m * 64 + (((ke >> 3) ^ (m & 7)) * 8) + (ke & 7)] =
                    *reinterpret_cast<short*>(&hb);
            }
        __syncthreads();                 // sY visible

        // ---- GEMM2: oacc[wm*32..+32][wn*64..+64] += Yc @ w2c^T ----
#pragma unroll
        for (int kk = 0; kk < 2; ++kk) {
            short8 a2[2];
#pragma unroll
            for (int i = 0; i < 2; ++i) {
                int m = wm * 32 + i * 16 + ra;
                a2[i] = *reinterpret_cast<const short8*>(
                    &sY[m * 64 + (((kk * 4 + q) ^ (ra & 7)) * 8)]);
            }
#pragma unroll
            for (int j = 0; j < 4; ++j) {
                int v = wn * 64 + j * 16 + ra;
                short8 b2 = *reinterpret_cast<const short8*>(
                    &sW2[p][v * 64 + (((kk * 4 + q) ^ (ra & 7)) * 8)]);
#pragma unroll
                for (int i = 0; i < 2; ++i)
                    oacc[i][j] = __builtin_amdgcn_mfma_f32_16x16x32_bf16(a2[i], b2, oacc[i][j], 0, 0, 0);
            }
        }
    }

    // ---- epilogue: stage mlp result to LDS (stride 260 floats) ----
    __syncthreads();                     // all GEMM2 LDS reads done before alias
    float* sOut = reinterpret_cast<float*>(smem);   // 64 x 260 floats = 66.5 KB
#pragma unroll
    for (int i = 0; i < 2; ++i)
#pragma unroll
        for (int j = 0; j < 4; ++j)
#pragma unroll
            for (int reg = 0; reg < 4; ++reg) {
                int l = wm * 32 + i * 16 + q * 4 + reg;
                int col = wn * 64 + j * 16 + ra;
                sOut[l * 260 + col] = oacc[i][j][reg];
            }
    __syncthreads();

    // ---- fused attention emit: out = attn + mlp ----
    {
        int v    = threadIdx.x & 255;
        int half = threadIdx.x >> 8;
        int b  = m0 >> 11;               // / NN
        int n0 = m0 & (NN - 1);
        int r0 = n0 + half * RPC;        // this thread's chunk start row
        float wvv = wv[v];
        float vb  = v_bos[v];
        float S = chunkSum[((size_t)b * CHK + (r0 >> 5)) * VV + v];
        float prev = 0.f;
        int r = r0;
        if (r0 == 0) {
            out[((size_t)b * NN) * VV + v] = vb + sOut[0 * 260 + v];
            r = 1;
        } else {
            short p = Xb[((size_t)b * NN + r0 - 1) * VV + v];
            prev = bf16s_to_f(p) * wvv;
        }
#pragma unroll 4
        for (; r < r0 + RPC; ++r) {
            size_t idx = ((size_t)b * NN + r) * VV + v;
            float val = bf16s_to_f(Xb[idx]) * wvv;
            S += val;
            float4 wp4 = *reinterpret_cast<const float4*>(wpack + (size_t)(b * NN + r) * 4);
            float o = wp4.x * vb + wp4.y * prev + wp4.z * S;
            prev = val;
            out[idx] = o + sOut[(r - n0) * 260 + v];
        }
    }
}

// ---------------------------------------------------------------------------
extern "C" void kernel_launch(void* const* d_in, const int* in_sizes, int n_in,
                              void* d_out, int out_size, void* d_ws, size_t ws_size,
                              hipStream_t stream)
{
    const float* h        = (const float*)d_in[0];
    const float* ln_attn_g = (const float*)d_in[3];
    const float* ln_attn_b = (const float*)d_in[4];
    const float* ln_mlp_g  = (const float*)d_in[5];
    const float* ln_mlp_b  = (const float*)d_in[6];
    const float* wv        = (const float*)d_in[7];
    const float* wv_bos    = (const float*)d_in[8];
    const float* wo_w      = (const float*)d_in[9];
    const float* qk_bos    = (const float*)d_in[10];
    const float* qk_prev   = (const float*)d_in[11];
    const float* qk_dir    = (const float*)d_in[12];
    const float* w1        = (const float*)d_in[13];
    const float* w2        = (const float*)d_in[14];
    float* out = (float*)d_out;

    float* attn_row0 = (float*)d_ws;                 // 2048
    float* mlp_row0  = attn_row0 + BB * VV;          // 2048
    float* v_bos     = mlp_row0 + BB * VV;           // 256
    float* sum0      = v_bos + VV;                   // 8
    float* wpack     = sum0 + 8;                     // BB*NN*4 = 65536 (16B aligned)
    float* chunkSum  = wpack + (size_t)BB * NN * 4;  // BB*CHK*VV = 131072
    short* Xb        = (short*)(chunkSum + BB * CHK * VV);
    short* w1b       = (short*)(Xb + (size_t)BB * NN * VV);
    short* w2b       = w1b + HH * VV;

    prep_kernel<<<BB + 1, 256, 0, stream>>>(h, ln_attn_g, ln_attn_b, ln_mlp_g, ln_mlp_b,
                                            qk_dir, wo_w, wv_bos,
                                            attn_row0, mlp_row0, v_bos, sum0);
    scan_qkw_cvt_kernel<<<BB * CHK, 256, 0, stream>>>(h, mlp_row0, wv, qk_bos, qk_prev,
                                                      sum0, Xb, wpack, chunkSum,
                                                      w1, w2, w1b, w2b);
    chunkscan_kernel<<<BB, 256, 0, stream>>>(chunkSum);
    mlp_fused4<<<256, 512, 0, stream>>>(Xb, w1b, w2b, wv, v_bos, wpack, chunkSum, out);
}

// Round 2
// 154.353 us; speedup vs baseline: 1.1211x; 1.0570x over previous
//
#include <hip/hip_runtime.h>
#include <hip/hip_bf16.h>

#define BB 8
#define NN 2048
#define VV 256
#define HH 1024
#define CHK 64
#define RPC 32
constexpr float EPS = 1e-5f;

typedef __attribute__((ext_vector_type(4))) float floatx4;
typedef __attribute__((ext_vector_type(8))) short short8;

__device__ __forceinline__ void load_lds16(const void* g, void* l) {
    __builtin_amdgcn_global_load_lds((const __attribute__((address_space(1))) void*)g,
                                     (__attribute__((address_space(3))) void*)l, 16, 0, 0);
}
__device__ __forceinline__ float bf16s_to_f(short s) {
    unsigned u = ((unsigned)(unsigned short)s) << 16;
    return __builtin_bit_cast(float, u);
}

// ---------------------------------------------------------------------------
// K1: fused scan pass. Per block (b, chunk c of 32 rows):
//   - redundant in-block LN of h[b,0,:] (attn + mlp): gives s0b = attn_ln.qk_dir
//     and the mlp row-0 swap values, killing the old prep kernel round-trip.
//   - bf16 convert of h (BOS row swap), packed softmax weights {W0,WP-WZ,WZ,0},
//     chunk partial sums of wv-weighted values.
//   - weight bf16 conversion tail (1 float4/thread: 512x256 = 2*H*V/4 exact).
//   - block 0 additionally computes v_bos = wo_w @ wv_bos.
// ---------------------------------------------------------------------------
__global__ __launch_bounds__(256) void scan_fused_kernel(
    const float* __restrict__ h,
    const float* __restrict__ g_attn, const float* __restrict__ b_attn,
    const float* __restrict__ g_mlp,  const float* __restrict__ b_mlp,
    const float* __restrict__ qk_dir,
    const float* __restrict__ wo_w,  const float* __restrict__ wv_bos,
    const float* __restrict__ wv,
    const float* __restrict__ qk_bos, const float* __restrict__ qk_prev,
    short* __restrict__ Xb,
    float* __restrict__ wpack,
    float* __restrict__ chunkSum,
    float* __restrict__ v_bos,
    const float* __restrict__ w1, const float* __restrict__ w2,
    short* __restrict__ w1b, short* __restrict__ w2b)
{
    __shared__ float lds[4][VV];
    __shared__ __align__(16) float mrow[VV];
    __shared__ float redA[4], redB[4], redC[4];
    int t = threadIdx.x;
    int wave = t >> 6, lane = t & 63;
    int b = blockIdx.x / CHK, c = blockIdx.x % CHK;

    // ---- in-block LN of row 0 (both branches) + s0b ----
    float x0 = h[(size_t)b * NN * VV + t];
    float s = x0;
    for (int off = 32; off > 0; off >>= 1) s += __shfl_down(s, off);
    if (lane == 0) redA[wave] = s;
    __syncthreads();
    float m = (redA[0] + redA[1] + redA[2] + redA[3]) * (1.0f / VV);
    float xc = x0 - m;
    float sv = xc * xc;
    for (int off = 32; off > 0; off >>= 1) sv += __shfl_down(sv, off);
    if (lane == 0) redB[wave] = sv;
    __syncthreads();
    float var = (redB[0] + redB[1] + redB[2] + redB[3]) * (1.0f / VV);
    float inv = 1.0f / sqrtf(var + EPS);
    float an = xc * inv * g_attn[t] + b_attn[t];
    float mn = xc * inv * g_mlp[t]  + b_mlp[t];
    float sd = an * qk_dir[t];
    for (int off = 32; off > 0; off >>= 1) sd += __shfl_down(sd, off);
    if (lane == 0) redC[wave] = sd;
    mrow[t] = mn;
    __syncthreads();
    float s0b = redC[0] + redC[1] + redC[2] + redC[3];

    // ---- main scan over this chunk's 32 rows (8 per wave) ----
    int r0 = c * RPC + wave * 8;
    float4 wv4 = reinterpret_cast<const float4*>(wv)[lane];
    float4 qb4 = reinterpret_cast<const float4*>(qk_bos)[lane];
    float4 qp4 = reinterpret_cast<const float4*>(qk_prev)[lane];
    float4 vsum = {0.f, 0.f, 0.f, 0.f};
#pragma unroll
    for (int rr = 0; rr < 8; ++rr) {
        int r = r0 + rr;
        size_t base = ((size_t)b * NN + r) * VV;
        float4 x = *reinterpret_cast<const float4*>(h + base + lane * 4);
        float4 xs = x;
        if (r == 0) xs = *reinterpret_cast<const float4*>(&mrow[lane * 4]);
        __hip_bfloat16 c0 = __float2bfloat16(xs.x), c1 = __float2bfloat16(xs.y),
                       c2 = __float2bfloat16(xs.z), c3 = __float2bfloat16(xs.w);
        short4 pk;
        pk.x = *reinterpret_cast<short*>(&c0);
        pk.y = *reinterpret_cast<short*>(&c1);
        pk.z = *reinterpret_cast<short*>(&c2);
        pk.w = *reinterpret_cast<short*>(&c3);
        *reinterpret_cast<short4*>(Xb + base + lane * 4) = pk;
        if (r != 0) {
            vsum.x += bf16s_to_f(pk.x) * wv4.x; vsum.y += bf16s_to_f(pk.y) * wv4.y;
            vsum.z += bf16s_to_f(pk.z) * wv4.z; vsum.w += bf16s_to_f(pk.w) * wv4.w;
        }
        float s1 = x.x * qb4.x + x.y * qb4.y + x.z * qb4.z + x.w * qb4.w;
        float s2 = x.x * qp4.x + x.y * qp4.y + x.z * qp4.z + x.w * qp4.w;
        for (int off = 32; off > 0; off >>= 1) {
            s1 += __shfl_down(s1, off);
            s2 += __shfl_down(s2, off);
        }
        if (lane == 0) {
            int gid = b * NN + r;
            float W0, WP, WZ;
            if (r == 0) { W0 = 1.f; WP = 0.f; WZ = 0.f; }
            else if (r == 1) {
                float a = s1 * s0b + s2;
                float mm = fmaxf(a, 0.f);
                float ea = expf(a - mm), ez = expf(-mm);
                float Z = ea + ez;
                W0 = ea / Z; WZ = ez / Z; WP = WZ;
            } else {
                float a = s1 * s0b;
                float mm = fmaxf(fmaxf(a, s2), 0.f);
                float ea = expf(a - mm), ed = expf(s2 - mm), ez = expf(-mm);
                float Z = ea + ed + (float)(r - 1) * ez;
                W0 = ea / Z; WP = ed / Z; WZ = ez / Z;
            }
            float4 wp4 = {W0, WP - WZ, WZ, 0.f};
            *reinterpret_cast<float4*>(wpack + (size_t)gid * 4) = wp4;
        }
    }
    reinterpret_cast<float4*>(lds[wave])[lane] = vsum;

    // ---- fused weight conversion tail ----
    {
        int gi = blockIdx.x * 256 + threadIdx.x;   // float4 index, exact cover
        size_t off = (size_t)gi * 4;
        const float* src; short* dst;
        if (off < (size_t)HH * VV) { src = w1 + off; dst = w1b + off; }
        else                       { src = w2 + (off - (size_t)HH * VV); dst = w2b + (off - (size_t)HH * VV); }
        float4 x = *reinterpret_cast<const float4*>(src);
        __hip_bfloat16 c0 = __float2bfloat16(x.x), c1 = __float2bfloat16(x.y),
                       c2 = __float2bfloat16(x.z), c3 = __float2bfloat16(x.w);
        short4 pk;
        pk.x = *reinterpret_cast<short*>(&c0);
        pk.y = *reinterpret_cast<short*>(&c1);
        pk.z = *reinterpret_cast<short*>(&c2);
        pk.w = *reinterpret_cast<short*>(&c3);
        *reinterpret_cast<short4*>(dst) = pk;
    }

    // ---- block 0: v_bos = wo_w @ wv_bos ----
    if (blockIdx.x == 0) {
        const float4* wp = reinterpret_cast<const float4*>(wo_w + (size_t)t * VV);
        const float4* vp = reinterpret_cast<const float4*>(wv_bos);
        float acc = 0.f;
        for (int j = 0; j < VV / 4; ++j) {
            float4 a = wp[j], bq = vp[j];
            acc += a.x * bq.x + a.y * bq.y + a.z * bq.z + a.w * bq.w;
        }
        v_bos[t] = acc;
    }

    __syncthreads();
    int v = threadIdx.x;
    chunkSum[((size_t)b * CHK + c) * VV + v] = lds[0][v] + lds[1][v] + lds[2][v] + lds[3][v];
}

// ---------------------------------------------------------------------------
// K2: fused MLP + chunk-prefix + attention emit.
//   Core GEMM loop identical to the verified mlp_fused3/4 (double-buffered DMA
//   staging, XOR seg-swizzle, GEMM1 32x16 / GEMM2 32x64 wave tiles).
//   Prologue: each thread computes its exclusive chunk prefix from the RAW
//   chunkSum partials (<=63 coalesced L2-hot loads, held in 1 VGPR across the
//   GEMM, same c-order summation as the old chunkscan kernel -> bit-identical).
//   Epilogue: oacc -> LDS (stride 260), then the serial attention scan and a
//   single coalesced out = attn + mlp store.
// ---------------------------------------------------------------------------
__global__ __launch_bounds__(512) void mlp_fused5(const short* __restrict__ Xb,
                                                  const short* __restrict__ w1b,
                                                  const short* __restrict__ w2b,
                                                  const float* __restrict__ wv,
                                                  const float* __restrict__ v_bos,
                                                  const float* __restrict__ wpack,
                                                  const float* __restrict__ chunkSum,
                                                  float* __restrict__ out)
{
    __shared__ __align__(16) char smem[136 * 1024];
    short (*sW1)[64 * 256] = reinterpret_cast<short(*)[64 * 256]>(smem);           // 2 x 32 KB
    short (*sW2)[256 * 64] = reinterpret_cast<short(*)[256 * 64]>(smem + 65536);   // 2 x 32 KB
    short* sY = reinterpret_cast<short*>(smem + 131072);                            // 8 KB

    int wave = threadIdx.x >> 6, lane = threadIdx.x & 63;
    int wm = wave >> 2, wn = wave & 3;
    int ra = lane & 15, q = lane >> 4;
    int m0 = blockIdx.x * 64;
    int bq = m0 >> 11;                   // batch index
    int n0 = m0 & (NN - 1);              // row offset within batch

    auto stage = [&](int hc, int buf) {
#pragma unroll
        for (int it = 0; it < 4; ++it) {
            int g = wave * 4 + it;
            int n = g * 2 + (lane >> 5);
            int slot = lane & 31;
            load_lds16(w1b + (size_t)(hc * 64 + n) * VV + (slot ^ (n & 7)) * 8,
                       &sW1[buf][g * 512]);
        }
#pragma unroll
        for (int it = 0; it < 4; ++it) {
            int g = wave * 4 + it;
            int v = g * 8 + (lane >> 3);
            int slot = lane & 7;
            load_lds16(w2b + (size_t)v * HH + hc * 64 + (slot ^ (v & 7)) * 8,
                       &sW2[buf][g * 512]);
        }
    };

    stage(0, 0);   // start DMA early; everything below overlaps with it

    // X fragments: rows of this wave's wm-half, full K=256
    short8 xf[8][2];
#pragma unroll
    for (int ks = 0; ks < 8; ++ks)
#pragma unroll
        for (int i = 0; i < 2; ++i)
            xf[ks][i] = *reinterpret_cast<const short8*>(
                Xb + (size_t)(m0 + wm * 32 + i * 16 + ra) * VV + ks * 32 + q * 8);

    // exclusive chunk prefix for the attention emit (old chunkscan, inlined)
    int vcol = threadIdx.x & 255;
    int half = threadIdx.x >> 8;
    int cpre = (n0 >> 5) + half;         // number of preceding chunks
    float Sreg = 0.f;
    {
        const float* cs = chunkSum + (size_t)(bq * CHK) * VV + vcol;
#pragma unroll 4
        for (int c2 = 0; c2 < cpre; ++c2) Sreg += cs[(size_t)c2 * VV];
    }

    floatx4 oacc[2][4];
#pragma unroll
    for (int i = 0; i < 2; ++i)
#pragma unroll
        for (int j = 0; j < 4; ++j) oacc[i][j] = floatx4{0.f, 0.f, 0.f, 0.f};

    for (int hc = 0; hc < 16; ++hc) {
        int p = hc & 1;
        __syncthreads();                 // buf[p] staged+visible; sY consumed
        if (hc < 15) stage(hc + 1, p ^ 1);

        // ---- GEMM1: Y[wm*32..+32][wn*16..+16] = X @ w1c^T ----
        floatx4 yacc[2];
        yacc[0] = floatx4{0.f, 0.f, 0.f, 0.f};
        yacc[1] = floatx4{0.f, 0.f, 0.f, 0.f};
        int nb = wn * 16 + ra;
#pragma unroll
        for (int ks = 0; ks < 8; ++ks) {
            short8 bfr = *reinterpret_cast<const short8*>(
                &sW1[p][nb * 256 + (((ks * 4 + q) ^ (ra & 7)) * 8)]);
#pragma unroll
            for (int i = 0; i < 2; ++i)
                yacc[i] = __builtin_amdgcn_mfma_f32_16x16x32_bf16(xf[ks][i], bfr, yacc[i], 0, 0, 0);
        }
        // relu -> bf16 -> sY (swizzled)
#pragma unroll
        for (int i = 0; i < 2; ++i)
#pragma unroll
            for (int reg = 0; reg < 4; ++reg) {
                int mrow_ = wm * 32 + i * 16 + q * 4 + reg;
                int ke = wn * 16 + ra;
                __hip_bfloat16 hb = __float2bfloat16(fmaxf(yacc[i][reg], 0.f));
                sY[mrow_ * 64 + (((ke >> 3) ^ (mrow_ & 7)) * 8) + (ke & 7)] =
                    *reinterpret_cast<short*>(&hb);
            }
        __syncthreads();                 // sY visible

        // ---- GEMM2: oacc[wm*32..+32][wn*64..+64] += Yc @ w2c^T ----
#pragma unroll
        for (int kk = 0; kk < 2; ++kk) {
            short8 a2[2];
#pragma unroll
            for (int i = 0; i < 2; ++i) {
                int mrow_ = wm * 32 + i * 16 + ra;
                a2[i] = *reinterpret_cast<const short8*>(
                    &sY[mrow_ * 64 + (((kk * 4 + q) ^ (ra & 7)) * 8)]);
            }
#pragma unroll
            for (int j = 0; j < 4; ++j) {
                int v = wn * 64 + j * 16 + ra;
                short8 b2 = *reinterpret_cast<const short8*>(
                    &sW2[p][v * 64 + (((kk * 4 + q) ^ (ra & 7)) * 8)]);
#pragma unroll
                for (int i = 0; i < 2; ++i)
                    oacc[i][j] = __builtin_amdgcn_mfma_f32_16x16x32_bf16(a2[i], b2, oacc[i][j], 0, 0, 0);
            }
        }
    }

    // ---- epilogue: stage mlp result to LDS (stride 260 floats) ----
    __syncthreads();                     // all GEMM2 LDS reads done before alias
    float* sOut = reinterpret_cast<float*>(smem);   // 64 x 260 floats = 66.5 KB
#pragma unroll
    for (int i = 0; i < 2; ++i)
#pragma unroll
        for (int j = 0; j < 4; ++j)
#pragma unroll
            for (int reg = 0; reg < 4; ++reg) {
                int l = wm * 32 + i * 16 + q * 4 + reg;
                int col = wn * 64 + j * 16 + ra;
                sOut[l * 260 + col] = oacc[i][j][reg];
            }
    __syncthreads();

    // ---- fused attention emit: out = attn + mlp ----
    {
        int r0 = n0 + half * RPC;        // this thread's chunk start row
        float wvv = wv[vcol];
        float vb  = v_bos[vcol];
        float S = Sreg;
        float prev = 0.f;
        int r = r0;
        if (r0 == 0) {
            out[((size_t)bq * NN) * VV + vcol] = vb + sOut[0 * 260 + vcol];
            r = 1;
        } else {
            short p = Xb[((size_t)bq * NN + r0 - 1) * VV + vcol];
            prev = bf16s_to_f(p) * wvv;
        }
#pragma unroll 4
        for (; r < r0 + RPC; ++r) {
            size_t idx = ((size_t)bq * NN + r) * VV + vcol;
            float val = bf16s_to_f(Xb[idx]) * wvv;
            S += val;
            float4 wp4 = *reinterpret_cast<const float4*>(wpack + (size_t)(bq * NN + r) * 4);
            float o = wp4.x * vb + wp4.y * prev + wp4.z * S;
            prev = val;
            out[idx] = o + sOut[(r - n0) * 260 + vcol];
        }
    }
}

// ---------------------------------------------------------------------------
extern "C" void kernel_launch(void* const* d_in, const int* in_sizes, int n_in,
                              void* d_out, int out_size, void* d_ws, size_t ws_size,
                              hipStream_t stream)
{
    const float* h        = (const float*)d_in[0];
    const float* ln_attn_g = (const float*)d_in[3];
    const float* ln_attn_b = (const float*)d_in[4];
    const float* ln_mlp_g  = (const float*)d_in[5];
    const float* ln_mlp_b  = (const float*)d_in[6];
    const float* wv        = (const float*)d_in[7];
    const float* wv_bos    = (const float*)d_in[8];
    const float* wo_w      = (const float*)d_in[9];
    const float* qk_bos    = (const float*)d_in[10];
    const float* qk_prev   = (const float*)d_in[11];
    const float* qk_dir    = (const float*)d_in[12];
    const float* w1        = (const float*)d_in[13];
    const float* w2        = (const float*)d_in[14];
    float* out = (float*)d_out;

    float* v_bos     = (float*)d_ws;                 // 256
    float* wpack     = v_bos + VV;                   // BB*NN*4 = 65536
    float* chunkSum  = wpack + (size_t)BB * NN * 4;  // BB*CHK*VV = 131072
    short* Xb        = (short*)(chunkSum + BB * CHK * VV);
    short* w1b       = (short*)(Xb + (size_t)BB * NN * VV);
    short* w2b       = w1b + HH * VV;

    scan_fused_kernel<<<BB * CHK, 256, 0, stream>>>(h, ln_attn_g, ln_attn_b,
                                                    ln_mlp_g, ln_mlp_b, qk_dir,
                                                    wo_w, wv_bos, wv, qk_bos, qk_prev,
                                                    Xb, wpack, chunkSum, v_bos,
                                                    w1, w2, w1b, w2b);
    mlp_fused5<<<256, 512, 0, stream>>>(Xb, w1b, w2b, wv, v_bos, wpack, chunkSum, out);
}